// Round 1
// baseline (516.042 us; speedup 1.0000x reference)
//
#include <hip/hip_runtime.h>
#include <math.h>

#define Bn  8
#define SQn 2048
#define SKn 2048
#define Hn  256
#define NHn 4
#define HDn 64
#define SCALEF 0.125f

typedef __attribute__((ext_vector_type(4))) float f32x4;
typedef __attribute__((ext_vector_type(8))) short short8;

__device__ __forceinline__ unsigned short f2bf(float f) {
  unsigned u = __builtin_bit_cast(unsigned, f);
  u += 0x7fffu + ((u >> 16) & 1u);
  return (unsigned short)(u >> 16);
}

__device__ __forceinline__ short8 load8f(const float* p) {
  float4 v0 = *(const float4*)p;
  float4 v1 = *(const float4*)(p + 4);
  short8 r;
  r[0] = (short)f2bf(v0.x); r[1] = (short)f2bf(v0.y);
  r[2] = (short)f2bf(v0.z); r[3] = (short)f2bf(v0.w);
  r[4] = (short)f2bf(v1.x); r[5] = (short)f2bf(v1.y);
  r[6] = (short)f2bf(v1.z); r[7] = (short)f2bf(v1.w);
  return r;
}

__device__ __forceinline__ f32x4 mfma16(short8 a, short8 b, f32x4 c) {
  return __builtin_amdgcn_mfma_f32_16x16x32_bf16(a, b, c, 0, 0, 0);
}

// ---------------------------------------------------------------- mask dtype
__global__ void detect_mask(const unsigned* __restrict__ m, int* __restrict__ flag) {
  if (threadIdx.x == 0) {
    int f = 0;
    for (int i = 0; i < 64; ++i)
      if (m[i] > 1u) f = 1;   // packed bytes -> values like 0x01010101
    flag[0] = f;
  }
}

// ------------------------------------------------- projection GEMM (f32 in)
// Y[m,n] = sum_k X[m,k]*W[n,k] + bias[n];  M=16384, N=K=256
// vtrans==0: Y stored [b][h][s][d] bf16 ;  vtrans==1: Y stored [b][h][d][s]
__global__ __launch_bounds__(256) void proj_kernel(
    const float* __restrict__ X, const float* __restrict__ W,
    const float* __restrict__ bias, unsigned short* __restrict__ Y, int vtrans)
{
  const int m0 = blockIdx.x * 64;
  const int n0 = blockIdx.y * 64;
  const int wv = threadIdx.x >> 6;
  const int l  = threadIdx.x & 63;
  const int lr = l & 15, lg = l >> 4;
  const int mrow = m0 + wv * 16 + lr;

  f32x4 acc[4];
  #pragma unroll
  for (int t = 0; t < 4; ++t) acc[t] = (f32x4){0.f, 0.f, 0.f, 0.f};

  const float* ap = X + (size_t)mrow * Hn + lg * 8;
  for (int k0 = 0; k0 < Hn; k0 += 32) {
    short8 a = load8f(ap + k0);
    #pragma unroll
    for (int t = 0; t < 4; ++t) {
      short8 bb = load8f(W + (size_t)(n0 + t * 16 + lr) * Hn + k0 + lg * 8);
      acc[t] = mfma16(a, bb, acc[t]);
    }
  }

  #pragma unroll
  for (int t = 0; t < 4; ++t) {
    const int n = n0 + t * 16 + lr;
    const float bv = bias[n];
    const int h = n >> 6, d = n & 63;
    if (!vtrans) {
      #pragma unroll
      for (int r = 0; r < 4; ++r) {
        const int m = m0 + wv * 16 + lg * 4 + r;
        const int bb = m >> 11, s = m & 2047;
        size_t idx = (((size_t)bb * NHn + h) * SQn + s) * HDn + d;
        Y[idx] = f2bf(acc[t][r] + bv);
      }
    } else {
      const int m = m0 + wv * 16 + lg * 4;
      const int bb = m >> 11, s = m & 2047;
      ushort4 pk;
      pk.x = f2bf(acc[t][0] + bv); pk.y = f2bf(acc[t][1] + bv);
      pk.z = f2bf(acc[t][2] + bv); pk.w = f2bf(acc[t][3] + bv);
      size_t idx = (((size_t)bb * NHn + h) * HDn + d) * (size_t)SKn + s;
      *(ushort4*)(Y + idx) = pk;
    }
  }
}

// --------------------------------------------------------- fused attention
template <typename T>
__device__ __forceinline__ void load_mask_bits(const T* __restrict__ mp, size_t rowbase,
                                               int colbase, int lr, unsigned mb[4]) {
  #pragma unroll
  for (int r = 0; r < 4; ++r) {
    const T* rp = mp + rowbase + (size_t)r * SKn + colbase + lr;
    unsigned bits = 0;
    #pragma unroll
    for (int t = 0; t < 16; ++t) bits |= (rp[t * 16] != 0 ? 1u : 0u) << t;
    mb[r] = bits;
  }
}

__global__ __launch_bounds__(512) void attn_kernel(
    const unsigned short* __restrict__ Qb, const unsigned short* __restrict__ Kb,
    const unsigned short* __restrict__ Vt, const void* __restrict__ maskp,
    const int* __restrict__ flagp, float* __restrict__ attn_out,
    unsigned short* __restrict__ Ob)
{
  __shared__ __align__(16) unsigned short Plds[16 * 2048];  // exactly 64 KiB
  float* red = (float*)Plds;         // [8][16] partials (aliased, barrier-ordered)
  float* gv  = (float*)Plds + 128;   // [16]

  const int q0 = blockIdx.x * 16;
  const int h = blockIdx.y, b = blockIdx.z;
  const int wv = threadIdx.x >> 6;          // 8 waves, 256 cols each
  const int l = threadIdx.x & 63;
  const int lr = l & 15, lg = l >> 4;
  const int colbase = wv * 256;
  const size_t bh = (size_t)b * NHn + h;

  const unsigned short* Qh = Qb + bh * SQn * HDn;
  const unsigned short* Kh = Kb + bh * SKn * HDn;
  const unsigned short* Vh = Vt + bh * HDn * SKn;

  short8 qa0 = *(const short8*)(Qh + (q0 + lr) * HDn + lg * 8);
  short8 qa1 = *(const short8*)(Qh + (q0 + lr) * HDn + 32 + lg * 8);

  // ---- scores S = Q K^T (per wave: 16 rows x 256 cols)
  f32x4 sc[16];
  #pragma unroll
  for (int t = 0; t < 16; ++t) {
    const int c0 = colbase + t * 16;
    short8 b0 = *(const short8*)(Kh + (size_t)(c0 + lr) * HDn + lg * 8);
    short8 b1 = *(const short8*)(Kh + (size_t)(c0 + lr) * HDn + 32 + lg * 8);
    f32x4 z = (f32x4){0.f, 0.f, 0.f, 0.f};
    z = mfma16(qa0, b0, z);
    z = mfma16(qa1, b1, z);
    sc[t] = z;
  }

  // ---- mask bits: per lane, 4 rows x 16 cols
  unsigned mb[4];
  const int q_base = q0 + lg * 4;
  const size_t mrowbase = ((size_t)b * SQn + q_base) * (size_t)SKn;
  if (*flagp) load_mask_bits((const unsigned char*)maskp, mrowbase, colbase, lr, mb);
  else        load_mask_bits((const int*)maskp,           mrowbase, colbase, lr, mb);

  // ---- row max (masked, scaled)
  float rmax[4] = {-INFINITY, -INFINITY, -INFINITY, -INFINITY};
  #pragma unroll
  for (int t = 0; t < 16; ++t)
    #pragma unroll
    for (int r = 0; r < 4; ++r)
      if ((mb[r] >> t) & 1) rmax[r] = fmaxf(rmax[r], sc[t][r] * SCALEF);
  #pragma unroll
  for (int m = 1; m < 16; m <<= 1)
    #pragma unroll
    for (int r = 0; r < 4; ++r)
      rmax[r] = fmaxf(rmax[r], __shfl_xor(rmax[r], m));
  if (lr == 0)
    #pragma unroll
    for (int r = 0; r < 4; ++r) red[wv * 16 + lg * 4 + r] = rmax[r];
  __syncthreads();
  if (threadIdx.x < 16) {
    float m = red[threadIdx.x];
    for (int w = 1; w < 8; ++w) m = fmaxf(m, red[w * 16 + threadIdx.x]);
    gv[threadIdx.x] = m;
  }
  __syncthreads();

  float gmax[4], rsum[4] = {0.f, 0.f, 0.f, 0.f};
  #pragma unroll
  for (int r = 0; r < 4; ++r) gmax[r] = gv[lg * 4 + r];

  // ---- p = exp(s - max); all-masked row -> one-hot at key 0 (mask-fix semantics)
  #pragma unroll
  for (int t = 0; t < 16; ++t) {
    const int col = colbase + t * 16 + lr;
    #pragma unroll
    for (int r = 0; r < 4; ++r) {
      float p;
      if (gmax[r] == -INFINITY) p = (col == 0) ? 1.0f : 0.0f;
      else p = ((mb[r] >> t) & 1) ? __expf(sc[t][r] * SCALEF - gmax[r]) : 0.0f;
      sc[t][r] = p;
      rsum[r] += p;
    }
  }
  #pragma unroll
  for (int m = 1; m < 16; m <<= 1)
    #pragma unroll
    for (int r = 0; r < 4; ++r) rsum[r] += __shfl_xor(rsum[r], m);
  if (lr == 0)
    #pragma unroll
    for (int r = 0; r < 4; ++r) red[wv * 16 + lg * 4 + r] = rsum[r];
  __syncthreads();
  if (threadIdx.x < 16) {
    float s = 0.f;
    for (int w = 0; w < 8; ++w) s += red[w * 16 + threadIdx.x];
    gv[threadIdx.x] = s;
  }
  __syncthreads();
  float rinv[4];
  #pragma unroll
  for (int r = 0; r < 4; ++r) rinv[r] = 1.0f / gv[lg * 4 + r];
  __syncthreads();  // everyone has rinv in regs before P clobbers red/gv region

  // ---- write attn (f32, global) + P (bf16, XOR-swizzled LDS)
  #pragma unroll
  for (int t = 0; t < 16; ++t) {
    const int col = colbase + t * 16 + lr;
    #pragma unroll
    for (int r = 0; r < 4; ++r) {
      const int row = lg * 4 + r;
      float a = sc[t][r] * rinv[r];
      attn_out[(bh * SQn + q0 + row) * (size_t)SKn + col] = a;
      unsigned byteoff = (unsigned)row * 4096u + (unsigned)col * 2u;
      byteoff ^= ((unsigned)(row & 7) << 4);
      *(unsigned short*)((char*)Plds + byteoff) = f2bf(a);
    }
  }
  __syncthreads();

  // ---- PV: partial O over this wave's 256 cols
  f32x4 oacc[4];
  #pragma unroll
  for (int dt = 0; dt < 4; ++dt) oacc[dt] = (f32x4){0.f, 0.f, 0.f, 0.f};
  #pragma unroll
  for (int ks = 0; ks < 8; ++ks) {
    const int ck = colbase + ks * 32;
    unsigned aoff = (unsigned)lr * 4096u + (unsigned)(ck + lg * 8) * 2u;
    aoff ^= ((unsigned)(lr & 7) << 4);
    short8 pa = *(const short8*)((char*)Plds + aoff);
    #pragma unroll
    for (int dt = 0; dt < 4; ++dt) {
      short8 vb = *(const short8*)(Vh + (size_t)(dt * 16 + lr) * SKn + ck + lg * 8);
      oacc[dt] = mfma16(pa, vb, oacc[dt]);
    }
  }
  __syncthreads();

  // ---- reduce partial O across 8 waves (reuse Plds as float [8][16][64])
  float* Op = (float*)Plds;
  #pragma unroll
  for (int dt = 0; dt < 4; ++dt)
    #pragma unroll
    for (int r = 0; r < 4; ++r)
      Op[(wv * 16 + lg * 4 + r) * 64 + dt * 16 + lr] = oacc[dt][r];
  __syncthreads();
  for (int e = threadIdx.x; e < 1024; e += 512) {
    const int row = e >> 6, d = e & 63;
    float s = 0.f;
    for (int w = 0; w < 8; ++w) s += Op[w * 1024 + row * 64 + d];
    Ob[((size_t)b * SQn + q0 + row) * Hn + h * HDn + d] = f2bf(s);
  }
}

// ------------------------------------------------ output projection (bf16 A)
__global__ __launch_bounds__(256) void oproj_kernel(
    const unsigned short* __restrict__ A, const float* __restrict__ W,
    const float* __restrict__ bias, float* __restrict__ out)
{
  const int m0 = blockIdx.x * 64;
  const int n0 = blockIdx.y * 64;
  const int wv = threadIdx.x >> 6;
  const int l  = threadIdx.x & 63;
  const int lr = l & 15, lg = l >> 4;
  const int mrow = m0 + wv * 16 + lr;

  f32x4 acc[4];
  #pragma unroll
  for (int t = 0; t < 4; ++t) acc[t] = (f32x4){0.f, 0.f, 0.f, 0.f};

  for (int k0 = 0; k0 < Hn; k0 += 32) {
    short8 a = *(const short8*)(A + (size_t)mrow * Hn + k0 + lg * 8);
    #pragma unroll
    for (int t = 0; t < 4; ++t) {
      short8 bb = load8f(W + (size_t)(n0 + t * 16 + lr) * Hn + k0 + lg * 8);
      acc[t] = mfma16(a, bb, acc[t]);
    }
  }
  #pragma unroll
  for (int t = 0; t < 4; ++t) {
    const int n = n0 + t * 16 + lr;
    const float bv = bias[n];
    #pragma unroll
    for (int r = 0; r < 4; ++r) {
      const int m = m0 + wv * 16 + lg * 4 + r;
      out[(size_t)m * Hn + n] = acc[t][r] + bv;
    }
  }
}

extern "C" void kernel_launch(void* const* d_in, const int* in_sizes, int n_in,
                              void* d_out, int out_size, void* d_ws, size_t ws_size,
                              hipStream_t stream) {
  const float* query = (const float*)d_in[0];
  const float* key_  = (const float*)d_in[1];
  const float* value = (const float*)d_in[2];
  const void*  mask  = d_in[3];
  const float* Wq = (const float*)d_in[4];
  const float* bq = (const float*)d_in[5];
  const float* Wk = (const float*)d_in[6];
  const float* bk = (const float*)d_in[7];
  const float* Wv = (const float*)d_in[8];
  const float* bv = (const float*)d_in[9];
  const float* Wo = (const float*)d_in[10];
  const float* bo = (const float*)d_in[11];

  float* out  = (float*)d_out;
  float* attn = out + (size_t)Bn * SQn * Hn;   // 4,194,304 f32 for `out`, rest attn

  char* ws = (char*)d_ws;
  int* flag = (int*)ws;
  unsigned short* Qb = (unsigned short*)(ws + 256);
  unsigned short* Kb = Qb + (size_t)Bn * SQn * Hn;
  unsigned short* Vt = Kb + (size_t)Bn * SKn * Hn;
  unsigned short* Ob = Vt + (size_t)Bn * SKn * Hn;

  detect_mask<<<1, 64, 0, stream>>>((const unsigned*)mask, flag);

  dim3 pg(256, 4);
  proj_kernel<<<pg, 256, 0, stream>>>(query, Wq, bq, Qb, 0);
  proj_kernel<<<pg, 256, 0, stream>>>(key_,  Wk, bk, Kb, 0);
  proj_kernel<<<pg, 256, 0, stream>>>(value, Wv, bv, Vt, 1);

  attn_kernel<<<dim3(SQn / 16, NHn, Bn), 512, 0, stream>>>(
      Qb, Kb, Vt, mask, flag, attn, Ob);

  oproj_kernel<<<dim3(256, 4), 256, 0, stream>>>(Ob, Wo, bo, out);
}